// Round 8
// baseline (1018.480 us; speedup 1.0000x reference)
//
#include <hip/hip_runtime.h>
#include <stdint.h>

#define N_NODES 50000
#define N_EDGES 640000
#define NODE_DIM 128
#define EDGE_DIM 16
#define UNITS 128
#define DOUT 256    // UNITS + NODE_DIM
#define SCAN_NB ((N_NODES + 255) / 256)   // 196 scan blocks

typedef __attribute__((ext_vector_type(4))) float v4f;
typedef __attribute__((ext_vector_type(8))) short v8s;
typedef __attribute__((ext_vector_type(4))) short v4s;
typedef __attribute__((ext_vector_type(2))) unsigned v2u;
typedef __attribute__((ext_vector_type(4))) unsigned v4u;

// round-half-up bf16 (2 VALU ops; tie bias irrelevant at 2% tol)
static __device__ __forceinline__ short f2bf(float f) {
    return (short)((__float_as_uint(f) + 0x8000u) >> 16);
}
static __device__ __forceinline__ float bf2f(short s) {
    return __uint_as_float(((unsigned)(unsigned short)s) << 16);
}
// pack two f32 -> bf16x2 dword: 2 adds + 1 v_perm
static __device__ __forceinline__ unsigned pack_bf2(float a, float b) {
    unsigned ua = __float_as_uint(a) + 0x8000u;
    unsigned ub = __float_as_uint(b) + 0x8000u;
    return __builtin_amdgcn_perm(ub, ua, 0x07060302);  // [ub.hi16 : ua.hi16]
}

// ---------------- zero counts ----------------
__global__ void k_zero(int* __restrict__ p, int n) {
    int i = blockIdx.x * 256 + threadIdx.x;
    if (i < n) p[i] = 0;
}

// ---------------- CSR build ----------------
__global__ void k_hist(const int* __restrict__ dst, int* __restrict__ counts) {
    int e = blockIdx.x * 256 + threadIdx.x;
    if (e < N_EDGES) atomicAdd(&counts[dst[e]], 1);
}

__global__ __launch_bounds__(256) void k_scan_part(const int* __restrict__ counts,
                                                   int* __restrict__ part) {
    __shared__ int red[256];
    int t = threadIdx.x;
    int i = blockIdx.x * 256 + t;
    red[t] = (i < N_NODES) ? counts[i] : 0;
    __syncthreads();
#pragma unroll
    for (int s = 128; s > 0; s >>= 1) {
        if (t < s) red[t] += red[t + s];
        __syncthreads();
    }
    if (t == 0) part[blockIdx.x] = red[0];
}

__global__ __launch_bounds__(256) void k_scan_base(const int* __restrict__ part,
                                                   int* __restrict__ base) {
    __shared__ int buf[2][256];
    int t = threadIdx.x;
    int v = (t < SCAN_NB) ? part[t] : 0;
    buf[0][t] = v;
    __syncthreads();
    int cur = 0;
#pragma unroll
    for (int s = 1; s < 256; s <<= 1) {
        int nv = buf[cur][t];
        if (t >= s) nv += buf[cur][t - s];
        buf[cur ^ 1][t] = nv;
        cur ^= 1;
        __syncthreads();
    }
    if (t < SCAN_NB) base[t] = buf[cur][t] - v;  // exclusive
}

__global__ __launch_bounds__(256) void k_scan_write(const int* __restrict__ counts,
                                                    const int* __restrict__ base,
                                                    int* __restrict__ rowptr,
                                                    int* __restrict__ cursor) {
    __shared__ int buf[2][256];
    int t = threadIdx.x;
    int i = blockIdx.x * 256 + t;
    int v = (i < N_NODES) ? counts[i] : 0;
    buf[0][t] = v;
    __syncthreads();
    int cur = 0;
#pragma unroll
    for (int s = 1; s < 256; s <<= 1) {
        int nv = buf[cur][t];
        if (t >= s) nv += buf[cur][t - s];
        buf[cur ^ 1][t] = nv;
        cur ^= 1;
        __syncthreads();
    }
    if (i < N_NODES) {
        int excl = buf[cur][t] - v + base[blockIdx.x];
        rowptr[i] = excl;
        cursor[i] = excl;
    }
    if (i == 0) rowptr[N_NODES] = N_EDGES;
}

__global__ void k_fill(const int* __restrict__ src, const int* __restrict__ dst,
                       int* __restrict__ cursor, int* __restrict__ csr_eid,
                       int* __restrict__ csr_src) {
    int e = blockIdx.x * 256 + threadIdx.x;
    if (e < N_EDGES) {
        int d = dst[e];
        int pos = atomicAdd(&cursor[d], 1);
        csr_eid[pos] = e;
        csr_src[pos] = src[e];
    }
}

// ------------- weight prep: transpose to [n][k] bf16 -------------
__global__ void k_prep(const float* __restrict__ Wi, const float* __restrict__ Wu,
                       const float* __restrict__ Wn, short* __restrict__ WtI1,
                       short* __restrict__ WtI2, short* __restrict__ WtU,
                       short* __restrict__ WtN) {
    int i = blockIdx.x * 256 + threadIdx.x;
    if (i < 128 * 128) {
        int n = i >> 7, k = i & 127;
        WtI1[i] = f2bf(Wi[k * UNITS + n]);
        return;
    }
    int j = i - 128 * 128;
    if (j < 128 * 32) {
        int n = j >> 5, k = j & 31;
        WtI2[j] = (k < EDGE_DIM) ? f2bf(Wi[(NODE_DIM + k) * UNITS + n]) : (short)0;
        return;
    }
    int l = j - 128 * 32;
    if (l < 128 * 128) {
        int n = l >> 7, k = l & 127;
        WtU[l] = f2bf(Wu[k * UNITS + n]);
        return;
    }
    int m = l - 128 * 128;
    if (m < 256 * 256) {
        int n = m >> 8, k = m & 255;
        WtN[m] = f2bf(Wn[k * DOUT + n]);
    }
}

// ------------- nfw = nf @ W1 (no bias/relu), bf16 out -------------
// epilogue staged through LDS -> 16B coalesced stores
__global__ __launch_bounds__(256) void k_nfw(
    const float* __restrict__ nf, const short* __restrict__ WtI1,
    short* __restrict__ nfw) {
    __shared__ __align__(16) short nT[32][UNITS + 8];
    int t = threadIdx.x;
    int i0 = blockIdx.x * 32;
#pragma unroll
    for (int i = 0; i < 4; ++i) {
        int idx = i * 256 + t;
        int row = idx >> 5, c4 = idx & 31;
        int ri = i0 + row; if (ri >= N_NODES) ri = N_NODES - 1;
        v4f v = *(const v4f*)&nf[(size_t)ri * NODE_DIM + c4 * 4];
        unsigned* dst = (unsigned*)&nT[row][c4 * 4];
        dst[0] = pack_bf2(v[0], v[1]);
        dst[1] = pack_bf2(v[2], v[3]);
    }
    __syncthreads();
    int w = t >> 6, lane = t & 63, quad = lane >> 4, l16 = lane & 15;
    v4f acc[2][2];
#pragma unroll
    for (int m = 0; m < 2; ++m)
#pragma unroll
        for (int n = 0; n < 2; ++n) { acc[m][n][0] = 0; acc[m][n][1] = 0; acc[m][n][2] = 0; acc[m][n][3] = 0; }
#pragma unroll
    for (int kc = 0; kc < 4; ++kc) {
        int ko = kc * 32 + quad * 8;
        v8s a0 = *(const v8s*)&nT[l16][ko];
        v8s a1 = *(const v8s*)&nT[16 + l16][ko];
        v8s b0 = *(const v8s*)&WtI1[(size_t)(w * 32 + l16) * UNITS + ko];
        v8s b1 = *(const v8s*)&WtI1[(size_t)(w * 32 + 16 + l16) * UNITS + ko];
        acc[0][0] = __builtin_amdgcn_mfma_f32_16x16x32_bf16(a0, b0, acc[0][0], 0, 0, 0);
        acc[1][0] = __builtin_amdgcn_mfma_f32_16x16x32_bf16(a1, b0, acc[1][0], 0, 0, 0);
        acc[0][1] = __builtin_amdgcn_mfma_f32_16x16x32_bf16(a0, b1, acc[0][1], 0, 0, 0);
        acc[1][1] = __builtin_amdgcn_mfma_f32_16x16x32_bf16(a1, b1, acc[1][1], 0, 0, 0);
    }
    __syncthreads();  // all waves done reading nT before in-place epilogue
#pragma unroll
    for (int m = 0; m < 2; ++m)
#pragma unroll
        for (int n = 0; n < 2; ++n)
#pragma unroll
            for (int r = 0; r < 4; ++r) {
                int row = m * 16 + quad * 4 + r;
                int col = w * 32 + n * 16 + l16;
                nT[row][col] = f2bf(acc[m][n][r]);
            }
    __syncthreads();
#pragma unroll
    for (int i = 0; i < 2; ++i) {
        int idx = i * 256 + t;
        int row = idx >> 4, c = idx & 15;
        if (i0 + row < N_NODES)
            *((v8s*)&nfw[(size_t)(i0 + row) * UNITS + c * 8]) = *(const v8s*)&nT[row][c * 8];
    }
}

// ------------- edge init: h[e] = relu(nfw[src[e]] + ef[e]@W2 + b_init), bf16 -------------
// 64-edge tile; reg-staged gather; in-LDS epilogue + 16B coalesced store-back
__global__ __launch_bounds__(256) void k_edge_init2(
    const float* __restrict__ ef, const int* __restrict__ esrc,
    const short* __restrict__ nfw, const short* __restrict__ WtI2,
    const float* __restrict__ bi, short* __restrict__ h) {
    __shared__ __align__(16) short efT[64][40];          // K=32 padded (cols 16..31 zero)
    __shared__ __align__(16) short nfwT[64][UNITS + 8];
    int t = threadIdx.x;
    int e0 = blockIdx.x * 64;
    // src indices: 16 threads/row -> L1 broadcast loads
    int r0 = t >> 4, c = t & 15;
    int s0 = esrc[e0 + r0];
    int s1 = esrc[e0 + 16 + r0];
    int s2 = esrc[e0 + 32 + r0];
    int s3 = esrc[e0 + 48 + r0];
    // nfw gather: 4 x 16B in flight per thread
    v8s n0 = *(const v8s*)&nfw[(size_t)s0 * UNITS + c * 8];
    v8s n1 = *(const v8s*)&nfw[(size_t)s1 * UNITS + c * 8];
    v8s n2 = *(const v8s*)&nfw[(size_t)s2 * UNITS + c * 8];
    v8s n3 = *(const v8s*)&nfw[(size_t)s3 * UNITS + c * 8];
    {
        int row = t >> 2, c4 = t & 3;
        v4f v = *(const v4f*)&ef[(size_t)(e0 + row) * EDGE_DIM + c4 * 4];
        unsigned* dst = (unsigned*)&efT[row][c4 * 4];
        dst[0] = pack_bf2(v[0], v[1]);
        dst[1] = pack_bf2(v[2], v[3]);
        unsigned* z = (unsigned*)&efT[row][16 + c4 * 4];
        z[0] = 0; z[1] = 0;
    }
    *((v8s*)&nfwT[r0][c * 8]) = n0;
    *((v8s*)&nfwT[16 + r0][c * 8]) = n1;
    *((v8s*)&nfwT[32 + r0][c * 8]) = n2;
    *((v8s*)&nfwT[48 + r0][c * 8]) = n3;
    __syncthreads();
    int w = t >> 6, lane = t & 63, quad = lane >> 4, l16 = lane & 15;
    v4f acc[4][2];
#pragma unroll
    for (int m = 0; m < 4; ++m)
#pragma unroll
        for (int n = 0; n < 2; ++n) { acc[m][n][0] = 0; acc[m][n][1] = 0; acc[m][n][2] = 0; acc[m][n][3] = 0; }
    {
        int ko = quad * 8;
        v8s b0 = *(const v8s*)&WtI2[(size_t)(w * 32 + l16) * 32 + ko];
        v8s b1 = *(const v8s*)&WtI2[(size_t)(w * 32 + 16 + l16) * 32 + ko];
#pragma unroll
        for (int m = 0; m < 4; ++m) {
            v8s a = *(const v8s*)&efT[m * 16 + l16][ko];
            acc[m][0] = __builtin_amdgcn_mfma_f32_16x16x32_bf16(a, b0, acc[m][0], 0, 0, 0);
            acc[m][1] = __builtin_amdgcn_mfma_f32_16x16x32_bf16(a, b1, acc[m][1], 0, 0, 0);
        }
    }
    // epilogue: residual + bias + relu, in place into nfwT (each wave owns its 32-col slice)
#pragma unroll
    for (int m = 0; m < 4; ++m)
#pragma unroll
        for (int n = 0; n < 2; ++n)
#pragma unroll
            for (int r = 0; r < 4; ++r) {
                int row = m * 16 + quad * 4 + r;
                int col = w * 32 + n * 16 + l16;
                float v = acc[m][n][r] + bf2f(nfwT[row][col]) + bi[col];
                nfwT[row][col] = f2bf(fmaxf(v, 0.f));
            }
    __syncthreads();
    // coalesced store-back: 16B/lane, full 256B rows
#pragma unroll
    for (int i = 0; i < 4; ++i) {
        int idx = i * 256 + t;
        int row = idx >> 4, cc = idx & 15;
        *((v8s*)&h[(size_t)(e0 + row) * UNITS + cc * 8]) = *(const v8s*)&nfwT[row][cc * 8];
    }
}

// ------------- edge-loop segment_sum: aggb[i] = bf16(sum h[e]) -------------
// wave = 1 node; eids preloaded per-lane; 16 rows in flight per wave.
// Loads are UNCONDITIONAL (junk lanes re-read edge 0's row -> L1 hit);
// predication via fmaf 0/1 mask; all shfls at full exec mask.
__global__ __launch_bounds__(256) void k_agg_bf(
    const short* __restrict__ h, const int* __restrict__ rowptr,
    const int* __restrict__ csr_eid, short* __restrict__ aggb) {
    int w = threadIdx.x >> 6, lane = threadIdx.x & 63;
    int node = blockIdx.x * 4 + w;
    int g = lane >> 4, l = lane & 15;
    int beg = rowptr[node], end = rowptr[node + 1];
    int deg = end - beg;
    int ev = (lane < deg) ? csr_eid[beg + lane] : 0;
    int dcap = deg < 64 ? deg : 64;
    float a[8];
#pragma unroll
    for (int k = 0; k < 8; ++k) a[k] = 0.f;
    for (int base = 0; base < dcap; base += 16) {   // wave-uniform trip count
        v8s u[4];
        float m[4];
#pragma unroll
        for (int q = 0; q < 4; ++q) {
            int jq = base + g + 4 * q;               // <= 63 always
            int eq = __shfl(ev, jq);                 // full exec mask
            u[q] = *(const v8s*)&h[(size_t)eq * UNITS + l * 8];
            m[q] = (jq < dcap) ? 1.f : 0.f;
        }
#pragma unroll
        for (int q = 0; q < 4; ++q)
#pragma unroll
            for (int k = 0; k < 8; ++k)
                a[k] = fmaf(m[q], bf2f(u[q][k]), a[k]);
    }
    for (int jj = 64 + g; jj < deg; jj += 4) {  // deg>64 safety net
        int ea = csr_eid[beg + jj];
        v8s u = *(const v8s*)&h[(size_t)ea * UNITS + l * 8];
#pragma unroll
        for (int k = 0; k < 8; ++k) a[k] += bf2f(u[k]);
    }
#pragma unroll
    for (int k = 0; k < 8; ++k) {
        a[k] += __shfl_xor(a[k], 16);
        a[k] += __shfl_xor(a[k], 32);
    }
    if (g == 0) {
        v4u o;
        o[0] = pack_bf2(a[0], a[1]); o[1] = pack_bf2(a[2], a[3]);
        o[2] = pack_bf2(a[4], a[5]); o[3] = pack_bf2(a[6], a[7]);
        *((v4u*)&aggb[(size_t)node * UNITS + l * 8]) = o;
    }
}

// ------------- final segment_sum (f32 out, for node phase) -------------
__global__ __launch_bounds__(256) void k_agg(
    const short* __restrict__ h, const int* __restrict__ rowptr,
    const int* __restrict__ csr_eid, float* __restrict__ agg) {
    int w = threadIdx.x >> 6, lane = threadIdx.x & 63;
    int node = blockIdx.x * 4 + w;
    int g = lane >> 4, l = lane & 15;
    int beg = rowptr[node], end = rowptr[node + 1];
    int deg = end - beg;
    int ev = (lane < deg) ? csr_eid[beg + lane] : 0;
    int dcap = deg < 64 ? deg : 64;
    float a[8];
#pragma unroll
    for (int k = 0; k < 8; ++k) a[k] = 0.f;
    for (int base = 0; base < dcap; base += 16) {
        v8s u[4];
        float m[4];
#pragma unroll
        for (int q = 0; q < 4; ++q) {
            int jq = base + g + 4 * q;
            int eq = __shfl(ev, jq);
            u[q] = *(const v8s*)&h[(size_t)eq * UNITS + l * 8];
            m[q] = (jq < dcap) ? 1.f : 0.f;
        }
#pragma unroll
        for (int q = 0; q < 4; ++q)
#pragma unroll
            for (int k = 0; k < 8; ++k)
                a[k] = fmaf(m[q], bf2f(u[q][k]), a[k]);
    }
    for (int jj = 64 + g; jj < deg; jj += 4) {
        int ea = csr_eid[beg + jj];
        v8s u = *(const v8s*)&h[(size_t)ea * UNITS + l * 8];
#pragma unroll
        for (int k = 0; k < 8; ++k) a[k] += bf2f(u[k]);
    }
#pragma unroll
    for (int k = 0; k < 8; ++k) {
        a[k] += __shfl_xor(a[k], 16);
        a[k] += __shfl_xor(a[k], 32);
    }
    if (g == 0) {
        v4f o0, o1;
        o0[0] = a[0]; o0[1] = a[1]; o0[2] = a[2]; o0[3] = a[3];
        o1[0] = a[4]; o1[1] = a[5]; o1[2] = a[6]; o1[3] = a[7];
        *((v4f*)&agg[(size_t)node * UNITS + l * 8]) = o0;
        *((v4f*)&agg[(size_t)node * UNITS + l * 8 + 4]) = o1;
    }
}

// ------------- fused edge step: h[e] = relu((aggb[src]-h[e^1]) @ W_upd + b + h[e]), in place -------------
// R7 structure with one register-pressure fix: hreg/areg are scoped to the
// msg phase only; the residual re-reads old h in the store phase (block's
// 16KB h segment is L2-hot from phase 1; same thread, same address, read
// happens before this thread's store -> identical values, race-free).
// MFMA-phase live set drops ~16 VGPRs -> launch_bounds(256,5) (cap 102,
// spill-proof even if the compiler CSEs the re-load) for 5 blocks/CU
// instead of ~3-4. R3 lesson: never set a cap the worst-case live set
// can violate (85 cap -> spill -> +170MB HBM).
__global__ __launch_bounds__(256, 5) void k_edge_step(
    const short* __restrict__ aggb, const int* __restrict__ esrc,
    const short* __restrict__ WtU, const float* __restrict__ bu,
    short* __restrict__ h) {
    __shared__ __align__(16) short msgT[64][UNITS + 8];
    int t = threadIdx.x;
    int e0 = blockIdx.x * 64;
    int srcv[4];
#pragma unroll
    for (int i = 0; i < 4; ++i) srcv[i] = esrc[e0 + ((i * 256 + t) >> 4)];
    {
        // phase 1: load h + aggb (8 x 16B in flight), build msg in LDS.
        // hreg/areg die at the end of this scope.
        v8s hreg[4], areg[4];
#pragma unroll
        for (int i = 0; i < 4; ++i) {
            int idx = i * 256 + t;
            int row = idx >> 4, c = idx & 15;
            hreg[i] = *(const v8s*)&h[(size_t)(e0 + row) * UNITS + c * 8];
            areg[i] = *(const v8s*)&aggb[(size_t)srcv[i] * UNITS + c * 8];
        }
        // msg = aggb[src] - h[rev]; h[rev] fragment lives in thread t^16
        // (row = idx>>4, lane bit 4 flips row bit 0 = e^1). All 64 lanes
        // active -> shfl defined.
#pragma unroll
        for (int i = 0; i < 4; ++i) {
            int idx = i * 256 + t;
            int row = idx >> 4, c = idx & 15;
            v4u hv = __builtin_bit_cast(v4u, hreg[i]);
            v4u rv;
#pragma unroll
            for (int k = 0; k < 4; ++k) rv[k] = (unsigned)__shfl_xor((int)hv[k], 16);
            v8s hr = __builtin_bit_cast(v8s, rv);
            unsigned* mrow = (unsigned*)&msgT[row][c * 8];
#pragma unroll
            for (int k = 0; k < 4; ++k) {
                float d0 = bf2f(areg[i][2 * k]) - bf2f(hr[2 * k]);
                float d1 = bf2f(areg[i][2 * k + 1]) - bf2f(hr[2 * k + 1]);
                mrow[k] = pack_bf2(d0, d1);
            }
        }
    }
    __syncthreads();
    int w = t >> 6, lane = t & 63, quad = lane >> 4, l16 = lane & 15;
    v4f acc[4][2];
#pragma unroll
    for (int m = 0; m < 4; ++m)
#pragma unroll
        for (int n = 0; n < 2; ++n) { acc[m][n][0] = 0; acc[m][n][1] = 0; acc[m][n][2] = 0; acc[m][n][3] = 0; }
#pragma unroll
    for (int kc = 0; kc < 4; ++kc) {
        int ko = kc * 32 + quad * 8;
        v8s b0 = *(const v8s*)&WtU[(size_t)(w * 32 + l16) * UNITS + ko];
        v8s b1 = *(const v8s*)&WtU[(size_t)(w * 32 + 16 + l16) * UNITS + ko];
#pragma unroll
        for (int m = 0; m < 4; ++m) {
            v8s a = *(const v8s*)&msgT[m * 16 + l16][ko];
            acc[m][0] = __builtin_amdgcn_mfma_f32_16x16x32_bf16(a, b0, acc[m][0], 0, 0, 0);
            acc[m][1] = __builtin_amdgcn_mfma_f32_16x16x32_bf16(a, b1, acc[m][1], 0, 0, 0);
        }
    }
    __syncthreads();  // all waves done reading msgT A-fragments
    // write bf16(acc + bias) into msgT (fragment layout); residual added after
#pragma unroll
    for (int m = 0; m < 4; ++m)
#pragma unroll
        for (int n = 0; n < 2; ++n)
#pragma unroll
            for (int r = 0; r < 4; ++r) {
                int row = m * 16 + quad * 4 + r;
                int col = w * 32 + n * 16 + l16;
                msgT[row][col] = f2bf(acc[m][n][r] + bu[col]);
            }
    __syncthreads();
    // store phase: re-read old h (L2-hot) + residual + relu + 16B store
#pragma unroll
    for (int i = 0; i < 4; ++i) {
        int idx = i * 256 + t;
        int row = idx >> 4, c = idx & 15;
        v8s hv = *(const v8s*)&h[(size_t)(e0 + row) * UNITS + c * 8];
        v8s mv = *(const v8s*)&msgT[row][c * 8];
        v4u o;
#pragma unroll
        for (int k = 0; k < 4; ++k) {
            float v0 = fmaxf(bf2f(mv[2 * k]) + bf2f(hv[2 * k]), 0.f);
            float v1 = fmaxf(bf2f(mv[2 * k + 1]) + bf2f(hv[2 * k + 1]), 0.f);
            o[k] = pack_bf2(v0, v1);
        }
        *((v4u*)&h[(size_t)(e0 + row) * UNITS + c * 8]) = o;
    }
}

// ------------- node init: x0 = (concat(nf, msg) * (1+eps)) @ W_node + b_node -------------
// also spills the bf16 concat tile to xcatb [N,256] for the first node step's gather
__global__ __launch_bounds__(256) void k_node_init(
    const float* __restrict__ nf, const float* __restrict__ msg,
    const short* __restrict__ WtN, const float* __restrict__ bn,
    const float* __restrict__ epsv, float* __restrict__ x0,
    short* __restrict__ xcatb) {
    __shared__ __align__(16) short xin[32][DOUT + 8];
    int t = threadIdx.x;
    int i0 = blockIdx.x * 32;
#pragma unroll
    for (int i = 0; i < 8; ++i) {
        int idx = i * 256 + t;
        int row = idx >> 6, c4 = idx & 63;
        int ri = i0 + row; if (ri >= N_NODES) ri = N_NODES - 1;
        int col = c4 * 4;
        v4f v;
        if (col < NODE_DIM) v = *(const v4f*)&nf[(size_t)ri * NODE_DIM + col];
        else v = *(const v4f*)&msg[(size_t)ri * UNITS + (col - NODE_DIM)];
        unsigned* dst = (unsigned*)&xin[row][col];
        dst[0] = pack_bf2(v[0], v[1]);
        dst[1] = pack_bf2(v[2], v[3]);
    }
    __syncthreads();
#pragma unroll
    for (int i = 0; i < 4; ++i) {
        int idx = i * 256 + t;
        int row = idx >> 5, c = idx & 31;
        int ri = i0 + row;
        if (ri < N_NODES) {
            v8s v = *(const v8s*)&xin[row][c * 8];
            *((v8s*)&xcatb[(size_t)ri * DOUT + c * 8]) = v;
        }
    }
    int w = t >> 6, lane = t & 63, quad = lane >> 4, l16 = lane & 15;
    v4f acc[2][4];
#pragma unroll
    for (int m = 0; m < 2; ++m)
#pragma unroll
        for (int n = 0; n < 4; ++n) { acc[m][n][0] = 0; acc[m][n][1] = 0; acc[m][n][2] = 0; acc[m][n][3] = 0; }
#pragma unroll
    for (int kc = 0; kc < 8; ++kc) {
        int ko = kc * 32 + quad * 8;
        v8s a0 = *(const v8s*)&xin[l16][ko];
        v8s a1 = *(const v8s*)&xin[16 + l16][ko];
#pragma unroll
        for (int n = 0; n < 4; ++n) {
            v8s b = *(const v8s*)&WtN[(size_t)(w * 64 + n * 16 + l16) * DOUT + ko];
            acc[0][n] = __builtin_amdgcn_mfma_f32_16x16x32_bf16(a0, b, acc[0][n], 0, 0, 0);
            acc[1][n] = __builtin_amdgcn_mfma_f32_16x16x32_bf16(a1, b, acc[1][n], 0, 0, 0);
        }
    }
    float scale = 1.f + epsv[0];
#pragma unroll
    for (int m = 0; m < 2; ++m)
#pragma unroll
        for (int n = 0; n < 4; ++n)
#pragma unroll
            for (int r = 0; r < 4; ++r) {
                int row = m * 16 + quad * 4 + r;
                int col = w * 64 + n * 16 + l16;
                if (i0 + row < N_NODES)
                    x0[(size_t)(i0 + row) * DOUT + col] = acc[m][n][r] * scale + bn[col];
            }
}

// ------------- node step (bf16 gather): out[i] = x0[i] + sum_{in-edges} xb[src[e]] -------------
// srcs preloaded per-lane + shfl at wave-uniform points; 8 rows in flight;
// unconditional loads (junk lanes hit node 0's cached row) + fmaf-mask acc
__global__ __launch_bounds__(256) void k_node_step_b(
    const short* __restrict__ xb, const float* __restrict__ x0,
    const int* __restrict__ rowptr, const int* __restrict__ csr_src,
    short* __restrict__ outb, float* __restrict__ outf, int writef) {
    int w = threadIdx.x >> 6, lane = threadIdx.x & 63;
    int node = blockIdx.x * 4 + w;
    int beg = rowptr[node], end = rowptr[node + 1];
    int deg = end - beg;
    int sv = (lane < deg) ? csr_src[beg + lane] : 0;
    int dcap = deg < 64 ? deg : 64;
    v4f xv = *(const v4f*)&x0[(size_t)node * DOUT + lane * 4];
    float a0 = xv[0], a1 = xv[1], a2 = xv[2], a3 = xv[3];
    for (int base = 0; base < dcap; base += 8) {   // wave-uniform
        v4s u[8];
        float m[8];
#pragma unroll
        for (int q = 0; q < 8; ++q) {
            int jq = base + q;                      // <= 63 always
            int sq = __shfl(sv, jq);                // full exec mask
            u[q] = *(const v4s*)&xb[(size_t)sq * DOUT + lane * 4];
            m[q] = (jq < dcap) ? 1.f : 0.f;
        }
#pragma unroll
        for (int q = 0; q < 8; ++q) {
            a0 = fmaf(m[q], bf2f(u[q][0]), a0);
            a1 = fmaf(m[q], bf2f(u[q][1]), a1);
            a2 = fmaf(m[q], bf2f(u[q][2]), a2);
            a3 = fmaf(m[q], bf2f(u[q][3]), a3);
        }
    }
    for (int jj = 64; jj < deg; ++jj) {  // deg>64 safety net
        int s0 = csr_src[beg + jj];
        v4s u0 = *(const v4s*)&xb[(size_t)s0 * DOUT + lane * 4];
        a0 += bf2f(u0[0]); a1 += bf2f(u0[1]); a2 += bf2f(u0[2]); a3 += bf2f(u0[3]);
    }
    if (writef) {
        v4f o; o[0] = a0; o[1] = a1; o[2] = a2; o[3] = a3;
        *((v4f*)&outf[(size_t)node * DOUT + lane * 4]) = o;
    } else {
        v2u o; o[0] = pack_bf2(a0, a1); o[1] = pack_bf2(a2, a3);
        *((v2u*)&outb[(size_t)node * DOUT + lane * 4]) = o;
    }
}

extern "C" void kernel_launch(void* const* d_in, const int* in_sizes, int n_in,
                              void* d_out, int out_size, void* d_ws, size_t ws_size,
                              hipStream_t stream) {
    const float* nf  = (const float*)d_in[0];
    const float* ef  = (const float*)d_in[1];
    const int* esrc  = (const int*)d_in[2];
    const int* edst  = (const int*)d_in[3];
    // d_in[4] = rev_edge: by construction rev_edge[e] == e^1; exploited in k_edge_step
    const float* Wi  = (const float*)d_in[5];
    const float* bi  = (const float*)d_in[6];
    const float* Wu  = (const float*)d_in[7];
    const float* bu  = (const float*)d_in[8];
    const float* Wn  = (const float*)d_in[9];
    const float* bn  = (const float*)d_in[10];
    const float* eps = (const float*)d_in[11];

    char* ws = (char*)d_ws;
    size_t off = 0;
    auto alloc = [&](size_t bytes) -> char* {
        char* p = ws + off;
        off += (bytes + 255) & ~(size_t)255;
        return p;
    };
    short* h     = (short*)alloc((size_t)N_EDGES * UNITS * 2);      // 163.84 MB
    float* x0    = (float*)h;                                        // node-phase aliases into h's region
    short* xcatb = (short*)((char*)h + (size_t)N_NODES * DOUT * 4);
    short* xbA   = (short*)((char*)xcatb + (size_t)N_NODES * DOUT * 2);
    short* xbB   = (short*)((char*)xbA + (size_t)N_NODES * DOUT * 2);
    char*  R     = alloc((size_t)N_NODES * UNITS * 4);               // nfw/aggb early; agg later
    short* nfw   = (short*)R;
    short* aggb  = (short*)(R + (size_t)N_NODES * UNITS * 2);
    float* agg   = (float*)R;
    int* counts  = (int*)alloc((size_t)N_NODES * 4);
    int* rowptr  = (int*)alloc((size_t)(N_NODES + 1) * 4);
    int* cursor  = (int*)alloc((size_t)N_NODES * 4);
    int* part    = (int*)alloc((size_t)SCAN_NB * 4);
    int* base    = (int*)alloc((size_t)SCAN_NB * 4);
    int* csr_eid = (int*)alloc((size_t)N_EDGES * 4);
    int* csr_src = (int*)alloc((size_t)N_EDGES * 4);
    short* WtI1  = (short*)alloc((size_t)128 * 128 * 2);
    short* WtI2  = (short*)alloc((size_t)128 * 32 * 2);
    short* WtU   = (short*)alloc((size_t)128 * 128 * 2);
    short* WtN   = (short*)alloc((size_t)256 * 256 * 2);
    float* xout  = (float*)d_out;

    if (ws_size < off) return;  // clean diagnostic failure instead of device fault

    k_zero<<<(N_NODES + 255) / 256, 256, 0, stream>>>(counts, N_NODES);
    k_hist<<<(N_EDGES + 255) / 256, 256, 0, stream>>>(edst, counts);
    k_scan_part<<<SCAN_NB, 256, 0, stream>>>(counts, part);
    k_scan_base<<<1, 256, 0, stream>>>(part, base);
    k_scan_write<<<SCAN_NB, 256, 0, stream>>>(counts, base, rowptr, cursor);
    k_fill<<<(N_EDGES + 255) / 256, 256, 0, stream>>>(esrc, edst, cursor, csr_eid, csr_src);
    k_prep<<<(128 * 128 + 128 * 32 + 128 * 128 + 256 * 256 + 255) / 256, 256, 0, stream>>>(
        Wi, Wu, Wn, WtI1, WtI2, WtU, WtN);

    k_nfw<<<(N_NODES + 31) / 32, 256, 0, stream>>>(nf, WtI1, nfw);
    k_edge_init2<<<N_EDGES / 64, 256, 0, stream>>>(ef, esrc, nfw, WtI2, bi, h);
    for (int s = 0; s < 4; ++s) {
        k_agg_bf<<<N_NODES / 4, 256, 0, stream>>>(h, rowptr, csr_eid, aggb);
        k_edge_step<<<N_EDGES / 64, 256, 0, stream>>>(aggb, esrc, WtU, bu, h);
    }
    k_agg<<<N_NODES / 4, 256, 0, stream>>>(h, rowptr, csr_eid, agg);
    // h dead from here; node-phase buffers overwrite its region (agg lives in R, separate)
    k_node_init<<<(N_NODES + 31) / 32, 256, 0, stream>>>(nf, agg, WtN, bn, eps, x0, xcatb);
    // step 1 aggregates x = concat(nf, msg) (reference semantics), from the bf16 spill
    k_node_step_b<<<N_NODES / 4, 256, 0, stream>>>(xcatb, x0, rowptr, csr_src, xbA, nullptr, 0);
    k_node_step_b<<<N_NODES / 4, 256, 0, stream>>>(xbA, x0, rowptr, csr_src, xbB, nullptr, 0);
    k_node_step_b<<<N_NODES / 4, 256, 0, stream>>>(xbB, x0, rowptr, csr_src, xbA, nullptr, 0);
    k_node_step_b<<<N_NODES / 4, 256, 0, stream>>>(xbA, x0, rowptr, csr_src, nullptr, xout, 1);
}

// Round 9
// 924.495 us; speedup vs baseline: 1.1017x; 1.1017x over previous
//
#include <hip/hip_runtime.h>
#include <stdint.h>

#define N_NODES 50000
#define N_EDGES 640000
#define NODE_DIM 128
#define EDGE_DIM 16
#define UNITS 128
#define DOUT 256    // UNITS + NODE_DIM
#define SCAN_NB ((N_NODES + 255) / 256)   // 196 scan blocks

typedef __attribute__((ext_vector_type(4))) float v4f;
typedef __attribute__((ext_vector_type(8))) short v8s;
typedef __attribute__((ext_vector_type(4))) short v4s;
typedef __attribute__((ext_vector_type(2))) unsigned v2u;
typedef __attribute__((ext_vector_type(4))) unsigned v4u;

// round-half-up bf16 (2 VALU ops; tie bias irrelevant at 2% tol)
static __device__ __forceinline__ short f2bf(float f) {
    return (short)((__float_as_uint(f) + 0x8000u) >> 16);
}
static __device__ __forceinline__ float bf2f(short s) {
    return __uint_as_float(((unsigned)(unsigned short)s) << 16);
}
// pack two f32 -> bf16x2 dword: 2 adds + 1 v_perm
static __device__ __forceinline__ unsigned pack_bf2(float a, float b) {
    unsigned ua = __float_as_uint(a) + 0x8000u;
    unsigned ub = __float_as_uint(b) + 0x8000u;
    return __builtin_amdgcn_perm(ub, ua, 0x07060302);  // [ub.hi16 : ua.hi16]
}

// ---------------- zero counts ----------------
__global__ void k_zero(int* __restrict__ p, int n) {
    int i = blockIdx.x * 256 + threadIdx.x;
    if (i < n) p[i] = 0;
}

// ---------------- CSR build ----------------
__global__ void k_hist(const int* __restrict__ dst, int* __restrict__ counts) {
    int e = blockIdx.x * 256 + threadIdx.x;
    if (e < N_EDGES) atomicAdd(&counts[dst[e]], 1);
}

__global__ __launch_bounds__(256) void k_scan_part(const int* __restrict__ counts,
                                                   int* __restrict__ part) {
    __shared__ int red[256];
    int t = threadIdx.x;
    int i = blockIdx.x * 256 + t;
    red[t] = (i < N_NODES) ? counts[i] : 0;
    __syncthreads();
#pragma unroll
    for (int s = 128; s > 0; s >>= 1) {
        if (t < s) red[t] += red[t + s];
        __syncthreads();
    }
    if (t == 0) part[blockIdx.x] = red[0];
}

__global__ __launch_bounds__(256) void k_scan_base(const int* __restrict__ part,
                                                   int* __restrict__ base) {
    __shared__ int buf[2][256];
    int t = threadIdx.x;
    int v = (t < SCAN_NB) ? part[t] : 0;
    buf[0][t] = v;
    __syncthreads();
    int cur = 0;
#pragma unroll
    for (int s = 1; s < 256; s <<= 1) {
        int nv = buf[cur][t];
        if (t >= s) nv += buf[cur][t - s];
        buf[cur ^ 1][t] = nv;
        cur ^= 1;
        __syncthreads();
    }
    if (t < SCAN_NB) base[t] = buf[cur][t] - v;  // exclusive
}

__global__ __launch_bounds__(256) void k_scan_write(const int* __restrict__ counts,
                                                    const int* __restrict__ base,
                                                    int* __restrict__ rowptr,
                                                    int* __restrict__ cursor) {
    __shared__ int buf[2][256];
    int t = threadIdx.x;
    int i = blockIdx.x * 256 + t;
    int v = (i < N_NODES) ? counts[i] : 0;
    buf[0][t] = v;
    __syncthreads();
    int cur = 0;
#pragma unroll
    for (int s = 1; s < 256; s <<= 1) {
        int nv = buf[cur][t];
        if (t >= s) nv += buf[cur][t - s];
        buf[cur ^ 1][t] = nv;
        cur ^= 1;
        __syncthreads();
    }
    if (i < N_NODES) {
        int excl = buf[cur][t] - v + base[blockIdx.x];
        rowptr[i] = excl;
        cursor[i] = excl;
    }
    if (i == 0) rowptr[N_NODES] = N_EDGES;
}

__global__ void k_fill(const int* __restrict__ src, const int* __restrict__ dst,
                       int* __restrict__ cursor, int* __restrict__ csr_eid,
                       int* __restrict__ csr_src) {
    int e = blockIdx.x * 256 + threadIdx.x;
    if (e < N_EDGES) {
        int d = dst[e];
        int pos = atomicAdd(&cursor[d], 1);
        csr_eid[pos] = e;
        csr_src[pos] = src[e];
    }
}

// ------------- weight prep: transpose to [n][k] bf16 -------------
__global__ void k_prep(const float* __restrict__ Wi, const float* __restrict__ Wu,
                       const float* __restrict__ Wn, short* __restrict__ WtI1,
                       short* __restrict__ WtI2, short* __restrict__ WtU,
                       short* __restrict__ WtN) {
    int i = blockIdx.x * 256 + threadIdx.x;
    if (i < 128 * 128) {
        int n = i >> 7, k = i & 127;
        WtI1[i] = f2bf(Wi[k * UNITS + n]);
        return;
    }
    int j = i - 128 * 128;
    if (j < 128 * 32) {
        int n = j >> 5, k = j & 31;
        WtI2[j] = (k < EDGE_DIM) ? f2bf(Wi[(NODE_DIM + k) * UNITS + n]) : (short)0;
        return;
    }
    int l = j - 128 * 32;
    if (l < 128 * 128) {
        int n = l >> 7, k = l & 127;
        WtU[l] = f2bf(Wu[k * UNITS + n]);
        return;
    }
    int m = l - 128 * 128;
    if (m < 256 * 256) {
        int n = m >> 8, k = m & 255;
        WtN[m] = f2bf(Wn[k * DOUT + n]);
    }
}

// ------------- nfw = nf @ W1 (no bias/relu), bf16 out -------------
// epilogue staged through LDS -> 16B coalesced stores
__global__ __launch_bounds__(256) void k_nfw(
    const float* __restrict__ nf, const short* __restrict__ WtI1,
    short* __restrict__ nfw) {
    __shared__ __align__(16) short nT[32][UNITS + 8];
    int t = threadIdx.x;
    int i0 = blockIdx.x * 32;
#pragma unroll
    for (int i = 0; i < 4; ++i) {
        int idx = i * 256 + t;
        int row = idx >> 5, c4 = idx & 31;
        int ri = i0 + row; if (ri >= N_NODES) ri = N_NODES - 1;
        v4f v = *(const v4f*)&nf[(size_t)ri * NODE_DIM + c4 * 4];
        unsigned* dst = (unsigned*)&nT[row][c4 * 4];
        dst[0] = pack_bf2(v[0], v[1]);
        dst[1] = pack_bf2(v[2], v[3]);
    }
    __syncthreads();
    int w = t >> 6, lane = t & 63, quad = lane >> 4, l16 = lane & 15;
    v4f acc[2][2];
#pragma unroll
    for (int m = 0; m < 2; ++m)
#pragma unroll
        for (int n = 0; n < 2; ++n) { acc[m][n][0] = 0; acc[m][n][1] = 0; acc[m][n][2] = 0; acc[m][n][3] = 0; }
#pragma unroll
    for (int kc = 0; kc < 4; ++kc) {
        int ko = kc * 32 + quad * 8;
        v8s a0 = *(const v8s*)&nT[l16][ko];
        v8s a1 = *(const v8s*)&nT[16 + l16][ko];
        v8s b0 = *(const v8s*)&WtI1[(size_t)(w * 32 + l16) * UNITS + ko];
        v8s b1 = *(const v8s*)&WtI1[(size_t)(w * 32 + 16 + l16) * UNITS + ko];
        acc[0][0] = __builtin_amdgcn_mfma_f32_16x16x32_bf16(a0, b0, acc[0][0], 0, 0, 0);
        acc[1][0] = __builtin_amdgcn_mfma_f32_16x16x32_bf16(a1, b0, acc[1][0], 0, 0, 0);
        acc[0][1] = __builtin_amdgcn_mfma_f32_16x16x32_bf16(a0, b1, acc[0][1], 0, 0, 0);
        acc[1][1] = __builtin_amdgcn_mfma_f32_16x16x32_bf16(a1, b1, acc[1][1], 0, 0, 0);
    }
    __syncthreads();  // all waves done reading nT before in-place epilogue
#pragma unroll
    for (int m = 0; m < 2; ++m)
#pragma unroll
        for (int n = 0; n < 2; ++n)
#pragma unroll
            for (int r = 0; r < 4; ++r) {
                int row = m * 16 + quad * 4 + r;
                int col = w * 32 + n * 16 + l16;
                nT[row][col] = f2bf(acc[m][n][r]);
            }
    __syncthreads();
#pragma unroll
    for (int i = 0; i < 2; ++i) {
        int idx = i * 256 + t;
        int row = idx >> 4, c = idx & 15;
        if (i0 + row < N_NODES)
            *((v8s*)&nfw[(size_t)(i0 + row) * UNITS + c * 8]) = *(const v8s*)&nT[row][c * 8];
    }
}

// ------------- edge init: h[e] = relu(nfw[src[e]] + ef[e]@W2 + b_init), bf16 -------------
// 64-edge tile; reg-staged gather; in-LDS epilogue + 16B coalesced store-back
__global__ __launch_bounds__(256) void k_edge_init2(
    const float* __restrict__ ef, const int* __restrict__ esrc,
    const short* __restrict__ nfw, const short* __restrict__ WtI2,
    const float* __restrict__ bi, short* __restrict__ h) {
    __shared__ __align__(16) short efT[64][40];          // K=32 padded (cols 16..31 zero)
    __shared__ __align__(16) short nfwT[64][UNITS + 8];
    int t = threadIdx.x;
    int e0 = blockIdx.x * 64;
    // src indices: 16 threads/row -> L1 broadcast loads
    int r0 = t >> 4, c = t & 15;
    int s0 = esrc[e0 + r0];
    int s1 = esrc[e0 + 16 + r0];
    int s2 = esrc[e0 + 32 + r0];
    int s3 = esrc[e0 + 48 + r0];
    // nfw gather: 4 x 16B in flight per thread
    v8s n0 = *(const v8s*)&nfw[(size_t)s0 * UNITS + c * 8];
    v8s n1 = *(const v8s*)&nfw[(size_t)s1 * UNITS + c * 8];
    v8s n2 = *(const v8s*)&nfw[(size_t)s2 * UNITS + c * 8];
    v8s n3 = *(const v8s*)&nfw[(size_t)s3 * UNITS + c * 8];
    {
        int row = t >> 2, c4 = t & 3;
        v4f v = *(const v4f*)&ef[(size_t)(e0 + row) * EDGE_DIM + c4 * 4];
        unsigned* dst = (unsigned*)&efT[row][c4 * 4];
        dst[0] = pack_bf2(v[0], v[1]);
        dst[1] = pack_bf2(v[2], v[3]);
        unsigned* z = (unsigned*)&efT[row][16 + c4 * 4];
        z[0] = 0; z[1] = 0;
    }
    *((v8s*)&nfwT[r0][c * 8]) = n0;
    *((v8s*)&nfwT[16 + r0][c * 8]) = n1;
    *((v8s*)&nfwT[32 + r0][c * 8]) = n2;
    *((v8s*)&nfwT[48 + r0][c * 8]) = n3;
    __syncthreads();
    int w = t >> 6, lane = t & 63, quad = lane >> 4, l16 = lane & 15;
    v4f acc[4][2];
#pragma unroll
    for (int m = 0; m < 4; ++m)
#pragma unroll
        for (int n = 0; n < 2; ++n) { acc[m][n][0] = 0; acc[m][n][1] = 0; acc[m][n][2] = 0; acc[m][n][3] = 0; }
    {
        int ko = quad * 8;
        v8s b0 = *(const v8s*)&WtI2[(size_t)(w * 32 + l16) * 32 + ko];
        v8s b1 = *(const v8s*)&WtI2[(size_t)(w * 32 + 16 + l16) * 32 + ko];
#pragma unroll
        for (int m = 0; m < 4; ++m) {
            v8s a = *(const v8s*)&efT[m * 16 + l16][ko];
            acc[m][0] = __builtin_amdgcn_mfma_f32_16x16x32_bf16(a, b0, acc[m][0], 0, 0, 0);
            acc[m][1] = __builtin_amdgcn_mfma_f32_16x16x32_bf16(a, b1, acc[m][1], 0, 0, 0);
        }
    }
    // epilogue: residual + bias + relu, in place into nfwT (each wave owns its 32-col slice)
#pragma unroll
    for (int m = 0; m < 4; ++m)
#pragma unroll
        for (int n = 0; n < 2; ++n)
#pragma unroll
            for (int r = 0; r < 4; ++r) {
                int row = m * 16 + quad * 4 + r;
                int col = w * 32 + n * 16 + l16;
                float v = acc[m][n][r] + bf2f(nfwT[row][col]) + bi[col];
                nfwT[row][col] = f2bf(fmaxf(v, 0.f));
            }
    __syncthreads();
    // coalesced store-back: 16B/lane, full 256B rows
#pragma unroll
    for (int i = 0; i < 4; ++i) {
        int idx = i * 256 + t;
        int row = idx >> 4, cc = idx & 15;
        *((v8s*)&h[(size_t)(e0 + row) * UNITS + cc * 8]) = *(const v8s*)&nfwT[row][cc * 8];
    }
}

// ------------- edge-loop segment_sum: aggb[i] = bf16(sum h[e]) -------------
// wave = 1 node; eids preloaded per-lane; 16 rows in flight per wave.
// Loads are UNCONDITIONAL (junk lanes re-read edge 0's row -> L1 hit);
// predication via fmaf 0/1 mask; all shfls at full exec mask.
// Also serves as the FINAL aggregation (bf16 out consumed by k_node_init).
__global__ __launch_bounds__(256) void k_agg_bf(
    const short* __restrict__ h, const int* __restrict__ rowptr,
    const int* __restrict__ csr_eid, short* __restrict__ aggb) {
    int w = threadIdx.x >> 6, lane = threadIdx.x & 63;
    int node = blockIdx.x * 4 + w;
    int g = lane >> 4, l = lane & 15;
    int beg = rowptr[node], end = rowptr[node + 1];
    int deg = end - beg;
    int ev = (lane < deg) ? csr_eid[beg + lane] : 0;
    int dcap = deg < 64 ? deg : 64;
    float a[8];
#pragma unroll
    for (int k = 0; k < 8; ++k) a[k] = 0.f;
    for (int base = 0; base < dcap; base += 16) {   // wave-uniform trip count
        v8s u[4];
        float m[4];
#pragma unroll
        for (int q = 0; q < 4; ++q) {
            int jq = base + g + 4 * q;               // <= 63 always
            int eq = __shfl(ev, jq);                 // full exec mask
            u[q] = *(const v8s*)&h[(size_t)eq * UNITS + l * 8];
            m[q] = (jq < dcap) ? 1.f : 0.f;
        }
#pragma unroll
        for (int q = 0; q < 4; ++q)
#pragma unroll
            for (int k = 0; k < 8; ++k)
                a[k] = fmaf(m[q], bf2f(u[q][k]), a[k]);
    }
    for (int jj = 64 + g; jj < deg; jj += 4) {  // deg>64 safety net
        int ea = csr_eid[beg + jj];
        v8s u = *(const v8s*)&h[(size_t)ea * UNITS + l * 8];
#pragma unroll
        for (int k = 0; k < 8; ++k) a[k] += bf2f(u[k]);
    }
#pragma unroll
    for (int k = 0; k < 8; ++k) {
        a[k] += __shfl_xor(a[k], 16);
        a[k] += __shfl_xor(a[k], 32);
    }
    if (g == 0) {
        v4u o;
        o[0] = pack_bf2(a[0], a[1]); o[1] = pack_bf2(a[2], a[3]);
        o[2] = pack_bf2(a[4], a[5]); o[3] = pack_bf2(a[6], a[7]);
        *((v4u*)&aggb[(size_t)node * UNITS + l * 8]) = o;
    }
}

// ------------- fused edge step: h[e] = relu((aggb[src]-h[e^1]) @ W_upd + b + h[e]), in place -------------
// R4/R7 structure verbatim -- measured structural optimum (80.2 µs, byte-
// minimal 321MB): single msgT buffer, 64-edge tile, 3 barriers, h[rev] via
// __shfl_xor(16), residual h in registers, launch_bounds(256,4) no-spill.
// Rejected by measurement: forced occupancy 6 (spill +170MB), 2-tile
// pipeline (VGPR 72, occ 28%), nt hints (+15 µs), L2 re-read (FETCH +60MB).
__global__ __launch_bounds__(256, 4) void k_edge_step(
    const short* __restrict__ aggb, const int* __restrict__ esrc,
    const short* __restrict__ WtU, const float* __restrict__ bu,
    short* __restrict__ h) {
    __shared__ __align__(16) short msgT[64][UNITS + 8];
    int t = threadIdx.x;
    int e0 = blockIdx.x * 64;
    // issue all global loads first (8 x 16B per thread in flight)
    int srcv[4];
#pragma unroll
    for (int i = 0; i < 4; ++i) srcv[i] = esrc[e0 + ((i * 256 + t) >> 4)];
    v8s hreg[4], areg[4];
#pragma unroll
    for (int i = 0; i < 4; ++i) {
        int idx = i * 256 + t;
        int row = idx >> 4, c = idx & 15;
        hreg[i] = *(const v8s*)&h[(size_t)(e0 + row) * UNITS + c * 8];
        areg[i] = *(const v8s*)&aggb[(size_t)srcv[i] * UNITS + c * 8];
    }
    // msg = aggb[src] - h[rev]; h[rev] fragment comes from thread t^16
    // (row = idx>>4, so lane bit 4 flips row bit 0 = e^1). All 64 lanes
    // active -> shfl defined.
#pragma unroll
    for (int i = 0; i < 4; ++i) {
        int idx = i * 256 + t;
        int row = idx >> 4, c = idx & 15;
        v4u hv = __builtin_bit_cast(v4u, hreg[i]);
        v4u rv;
#pragma unroll
        for (int k = 0; k < 4; ++k) rv[k] = (unsigned)__shfl_xor((int)hv[k], 16);
        v8s hr = __builtin_bit_cast(v8s, rv);
        unsigned* mrow = (unsigned*)&msgT[row][c * 8];
#pragma unroll
        for (int k = 0; k < 4; ++k) {
            float d0 = bf2f(areg[i][2 * k]) - bf2f(hr[2 * k]);
            float d1 = bf2f(areg[i][2 * k + 1]) - bf2f(hr[2 * k + 1]);
            mrow[k] = pack_bf2(d0, d1);
        }
    }
    __syncthreads();
    int w = t >> 6, lane = t & 63, quad = lane >> 4, l16 = lane & 15;
    v4f acc[4][2];
#pragma unroll
    for (int m = 0; m < 4; ++m)
#pragma unroll
        for (int n = 0; n < 2; ++n) { acc[m][n][0] = 0; acc[m][n][1] = 0; acc[m][n][2] = 0; acc[m][n][3] = 0; }
#pragma unroll
    for (int kc = 0; kc < 4; ++kc) {
        int ko = kc * 32 + quad * 8;
        v8s b0 = *(const v8s*)&WtU[(size_t)(w * 32 + l16) * UNITS + ko];
        v8s b1 = *(const v8s*)&WtU[(size_t)(w * 32 + 16 + l16) * UNITS + ko];
#pragma unroll
        for (int m = 0; m < 4; ++m) {
            v8s a = *(const v8s*)&msgT[m * 16 + l16][ko];
            acc[m][0] = __builtin_amdgcn_mfma_f32_16x16x32_bf16(a, b0, acc[m][0], 0, 0, 0);
            acc[m][1] = __builtin_amdgcn_mfma_f32_16x16x32_bf16(a, b1, acc[m][1], 0, 0, 0);
        }
    }
    __syncthreads();  // all waves done reading msgT A-fragments
    // write bf16(acc + bias) into msgT (fragment layout); residual added from regs after
#pragma unroll
    for (int m = 0; m < 4; ++m)
#pragma unroll
        for (int n = 0; n < 2; ++n)
#pragma unroll
            for (int r = 0; r < 4; ++r) {
                int row = m * 16 + quad * 4 + r;
                int col = w * 32 + n * 16 + l16;
                msgT[row][col] = f2bf(acc[m][n][r] + bu[col]);
            }
    __syncthreads();
    // load-layout read + in-register residual + relu + coalesced 16B store
#pragma unroll
    for (int i = 0; i < 4; ++i) {
        int idx = i * 256 + t;
        int row = idx >> 4, c = idx & 15;
        v8s mv = *(const v8s*)&msgT[row][c * 8];
        v4u o;
#pragma unroll
        for (int k = 0; k < 4; ++k) {
            float v0 = fmaxf(bf2f(mv[2 * k]) + bf2f(hreg[i][2 * k]), 0.f);
            float v1 = fmaxf(bf2f(mv[2 * k + 1]) + bf2f(hreg[i][2 * k + 1]), 0.f);
            o[k] = pack_bf2(v0, v1);
        }
        *((v4u*)&h[(size_t)(e0 + row) * UNITS + c * 8]) = o;
    }
}

// ------------- node init: x0 = (concat(nf, msgb) * (1+eps)) @ W_node + b_node -------------
// msg half read directly from aggb bf16 (k_agg deleted -- identical sums).
// x0 now stored bf16 (x0b): epilogue staged through xin LDS -> 16B coalesced
// stores; halves x0 bytes for the 4 node steps (128 MB total saved).
// Also spills the bf16 concat tile to xcatb [N,256] for step 1's gather.
__global__ __launch_bounds__(256) void k_node_init(
    const float* __restrict__ nf, const short* __restrict__ msgb,
    const short* __restrict__ WtN, const float* __restrict__ bn,
    const float* __restrict__ epsv, short* __restrict__ x0b,
    short* __restrict__ xcatb) {
    __shared__ __align__(16) short xin[32][DOUT + 8];
    int t = threadIdx.x;
    int i0 = blockIdx.x * 32;
#pragma unroll
    for (int i = 0; i < 8; ++i) {
        int idx = i * 256 + t;
        int row = idx >> 6, c4 = idx & 63;
        int ri = i0 + row; if (ri >= N_NODES) ri = N_NODES - 1;
        int col = c4 * 4;
        if (col < NODE_DIM) {
            v4f v = *(const v4f*)&nf[(size_t)ri * NODE_DIM + col];
            unsigned* dst = (unsigned*)&xin[row][col];
            dst[0] = pack_bf2(v[0], v[1]);
            dst[1] = pack_bf2(v[2], v[3]);
        } else {
            v4s u = *(const v4s*)&msgb[(size_t)ri * UNITS + (col - NODE_DIM)];
            *((v4s*)&xin[row][col]) = u;
        }
    }
    __syncthreads();
#pragma unroll
    for (int i = 0; i < 4; ++i) {
        int idx = i * 256 + t;
        int row = idx >> 5, c = idx & 31;
        int ri = i0 + row;
        if (ri < N_NODES) {
            v8s v = *(const v8s*)&xin[row][c * 8];
            *((v8s*)&xcatb[(size_t)ri * DOUT + c * 8]) = v;
        }
    }
    int w = t >> 6, lane = t & 63, quad = lane >> 4, l16 = lane & 15;
    v4f acc[2][4];
#pragma unroll
    for (int m = 0; m < 2; ++m)
#pragma unroll
        for (int n = 0; n < 4; ++n) { acc[m][n][0] = 0; acc[m][n][1] = 0; acc[m][n][2] = 0; acc[m][n][3] = 0; }
#pragma unroll
    for (int kc = 0; kc < 8; ++kc) {
        int ko = kc * 32 + quad * 8;
        v8s a0 = *(const v8s*)&xin[l16][ko];
        v8s a1 = *(const v8s*)&xin[16 + l16][ko];
#pragma unroll
        for (int n = 0; n < 4; ++n) {
            v8s b = *(const v8s*)&WtN[(size_t)(w * 64 + n * 16 + l16) * DOUT + ko];
            acc[0][n] = __builtin_amdgcn_mfma_f32_16x16x32_bf16(a0, b, acc[0][n], 0, 0, 0);
            acc[1][n] = __builtin_amdgcn_mfma_f32_16x16x32_bf16(a1, b, acc[1][n], 0, 0, 0);
        }
    }
    float scale = 1.f + epsv[0];
    __syncthreads();  // all waves done reading xin A-fragments
    // epilogue: bf16(acc*scale + bias) in place into xin (fragment layout)
#pragma unroll
    for (int m = 0; m < 2; ++m)
#pragma unroll
        for (int n = 0; n < 4; ++n)
#pragma unroll
            for (int r = 0; r < 4; ++r) {
                int row = m * 16 + quad * 4 + r;
                int col = w * 64 + n * 16 + l16;
                xin[row][col] = f2bf(acc[m][n][r] * scale + bn[col]);
            }
    __syncthreads();
    // coalesced x0b store: 16B/lane, full 512B rows
#pragma unroll
    for (int i = 0; i < 4; ++i) {
        int idx = i * 256 + t;
        int row = idx >> 5, c = idx & 31;
        int ri = i0 + row;
        if (ri < N_NODES)
            *((v8s*)&x0b[(size_t)ri * DOUT + c * 8]) = *(const v8s*)&xin[row][c * 8];
    }
}

// ------------- node step (bf16 gather): out[i] = x0b[i] + sum_{in-edges} xb[src[e]] -------------
// srcs preloaded per-lane + shfl at wave-uniform points; 8 rows in flight;
// unconditional loads (junk lanes hit node 0's cached row) + fmaf-mask acc.
// x0 read as bf16 (8B/lane) -- halves the x0 stream.
__global__ __launch_bounds__(256) void k_node_step_b(
    const short* __restrict__ xb, const short* __restrict__ x0b,
    const int* __restrict__ rowptr, const int* __restrict__ csr_src,
    short* __restrict__ outb, float* __restrict__ outf, int writef) {
    int w = threadIdx.x >> 6, lane = threadIdx.x & 63;
    int node = blockIdx.x * 4 + w;
    int beg = rowptr[node], end = rowptr[node + 1];
    int deg = end - beg;
    int sv = (lane < deg) ? csr_src[beg + lane] : 0;
    int dcap = deg < 64 ? deg : 64;
    v4s xv = *(const v4s*)&x0b[(size_t)node * DOUT + lane * 4];
    float a0 = bf2f(xv[0]), a1 = bf2f(xv[1]), a2 = bf2f(xv[2]), a3 = bf2f(xv[3]);
    for (int base = 0; base < dcap; base += 8) {   // wave-uniform
        v4s u[8];
        float m[8];
#pragma unroll
        for (int q = 0; q < 8; ++q) {
            int jq = base + q;                      // <= 63 always
            int sq = __shfl(sv, jq);                // full exec mask
            u[q] = *(const v4s*)&xb[(size_t)sq * DOUT + lane * 4];
            m[q] = (jq < dcap) ? 1.f : 0.f;
        }
#pragma unroll
        for (int q = 0; q < 8; ++q) {
            a0 = fmaf(m[q], bf2f(u[q][0]), a0);
            a1 = fmaf(m[q], bf2f(u[q][1]), a1);
            a2 = fmaf(m[q], bf2f(u[q][2]), a2);
            a3 = fmaf(m[q], bf2f(u[q][3]), a3);
        }
    }
    for (int jj = 64; jj < deg; ++jj) {  // deg>64 safety net
        int s0 = csr_src[beg + jj];
        v4s u0 = *(const v4s*)&xb[(size_t)s0 * DOUT + lane * 4];
        a0 += bf2f(u0[0]); a1 += bf2f(u0[1]); a2 += bf2f(u0[2]); a3 += bf2f(u0[3]);
    }
    if (writef) {
        v4f o; o[0] = a0; o[1] = a1; o[2] = a2; o[3] = a3;
        *((v4f*)&outf[(size_t)node * DOUT + lane * 4]) = o;
    } else {
        v2u o; o[0] = pack_bf2(a0, a1); o[1] = pack_bf2(a2, a3);
        *((v2u*)&outb[(size_t)node * DOUT + lane * 4]) = o;
    }
}

extern "C" void kernel_launch(void* const* d_in, const int* in_sizes, int n_in,
                              void* d_out, int out_size, void* d_ws, size_t ws_size,
                              hipStream_t stream) {
    const float* nf  = (const float*)d_in[0];
    const float* ef  = (const float*)d_in[1];
    const int* esrc  = (const int*)d_in[2];
    const int* edst  = (const int*)d_in[3];
    // d_in[4] = rev_edge: by construction rev_edge[e] == e^1; exploited in k_edge_step
    const float* Wi  = (const float*)d_in[5];
    const float* bi  = (const float*)d_in[6];
    const float* Wu  = (const float*)d_in[7];
    const float* bu  = (const float*)d_in[8];
    const float* Wn  = (const float*)d_in[9];
    const float* bn  = (const float*)d_in[10];
    const float* eps = (const float*)d_in[11];

    char* ws = (char*)d_ws;
    size_t off = 0;
    auto alloc = [&](size_t bytes) -> char* {
        char* p = ws + off;
        off += (bytes + 255) & ~(size_t)255;
        return p;
    };
    short* h     = (short*)alloc((size_t)N_EDGES * UNITS * 2);      // 163.84 MB
    short* x0b   = (short*)h;                                        // node-phase aliases into h's region (25.6MB)
    short* xcatb = (short*)((char*)h + (size_t)N_NODES * DOUT * 4);
    short* xbA   = (short*)((char*)xcatb + (size_t)N_NODES * DOUT * 2);
    short* xbB   = (short*)((char*)xbA + (size_t)N_NODES * DOUT * 2);
    char*  R     = alloc((size_t)N_NODES * UNITS * 4);               // nfw + aggb
    short* nfw   = (short*)R;
    short* aggb  = (short*)(R + (size_t)N_NODES * UNITS * 2);
    int* counts  = (int*)alloc((size_t)N_NODES * 4);
    int* rowptr  = (int*)alloc((size_t)(N_NODES + 1) * 4);
    int* cursor  = (int*)alloc((size_t)N_NODES * 4);
    int* part    = (int*)alloc((size_t)SCAN_NB * 4);
    int* base    = (int*)alloc((size_t)SCAN_NB * 4);
    int* csr_eid = (int*)alloc((size_t)N_EDGES * 4);
    int* csr_src = (int*)alloc((size_t)N_EDGES * 4);
    short* WtI1  = (short*)alloc((size_t)128 * 128 * 2);
    short* WtI2  = (short*)alloc((size_t)128 * 32 * 2);
    short* WtU   = (short*)alloc((size_t)128 * 128 * 2);
    short* WtN   = (short*)alloc((size_t)256 * 256 * 2);
    float* xout  = (float*)d_out;

    if (ws_size < off) return;  // clean diagnostic failure instead of device fault

    k_zero<<<(N_NODES + 255) / 256, 256, 0, stream>>>(counts, N_NODES);
    k_hist<<<(N_EDGES + 255) / 256, 256, 0, stream>>>(edst, counts);
    k_scan_part<<<SCAN_NB, 256, 0, stream>>>(counts, part);
    k_scan_base<<<1, 256, 0, stream>>>(part, base);
    k_scan_write<<<SCAN_NB, 256, 0, stream>>>(counts, base, rowptr, cursor);
    k_fill<<<(N_EDGES + 255) / 256, 256, 0, stream>>>(esrc, edst, cursor, csr_eid, csr_src);
    k_prep<<<(128 * 128 + 128 * 32 + 128 * 128 + 256 * 256 + 255) / 256, 256, 0, stream>>>(
        Wi, Wu, Wn, WtI1, WtI2, WtU, WtN);

    k_nfw<<<(N_NODES + 31) / 32, 256, 0, stream>>>(nf, WtI1, nfw);
    k_edge_init2<<<N_EDGES / 64, 256, 0, stream>>>(ef, esrc, nfw, WtI2, bi, h);
    for (int s = 0; s < 4; ++s) {
        k_agg_bf<<<N_NODES / 4, 256, 0, stream>>>(h, rowptr, csr_eid, aggb);
        k_edge_step<<<N_EDGES / 64, 256, 0, stream>>>(aggb, esrc, WtU, bu, h);
    }
    // final aggregation: same bf16 kernel; k_node_init consumes aggb directly
    k_agg_bf<<<N_NODES / 4, 256, 0, stream>>>(h, rowptr, csr_eid, aggb);
    // h dead from here; node-phase buffers overwrite its region (aggb in R, separate)
    k_node_init<<<(N_NODES + 31) / 32, 256, 0, stream>>>(nf, aggb, WtN, bn, eps, x0b, xcatb);
    // step 1 aggregates x = concat(nf, msg) (reference semantics), from the bf16 spill
    k_node_step_b<<<N_NODES / 4, 256, 0, stream>>>(xcatb, x0b, rowptr, csr_src, xbA, nullptr, 0);
    k_node_step_b<<<N_NODES / 4, 256, 0, stream>>>(xbA, x0b, rowptr, csr_src, xbB, nullptr, 0);
    k_node_step_b<<<N_NODES / 4, 256, 0, stream>>>(xbB, x0b, rowptr, csr_src, xbA, nullptr, 0);
    k_node_step_b<<<N_NODES / 4, 256, 0, stream>>>(xbA, x0b, rowptr, csr_src, nullptr, xout, 1);
}